// Round 3
// baseline (694.251 us; speedup 1.0000x reference)
//
#include <hip/hip_runtime.h>
#include <hip/hip_bf16.h>

#define N_SRCC 50000
#define N_DSTC 50000
#define N_EDG 800000
#define NBUK 500
#define DPB 100        // dst nodes per bucket; NBUK*DPB == N_DSTC
#define EPB 3334       // edges per partition block
#define NPB 240        // ceil(N_EDG/EPB)

typedef __attribute__((ext_vector_type(8))) short bf16x8;
typedef __attribute__((ext_vector_type(4))) float f32x4;

__device__ inline short f2bf(float x) {
  __hip_bfloat16 b = __float2bfloat16(x);
  return *reinterpret_cast<short*>(&b);
}
__device__ inline float bf2f(unsigned hi16) {  // hi16: bf16 bits in low 16
  union { unsigned u; float f; } c; c.u = hi16 << 16; return c.f;
}

// ---------------- fold: u[k,:] = sum_d a[k,d]*W[k*16+d,:], c[k] = sum_d a[k,d]*b[k*16+d]
__global__ void fold_kernel(const float* __restrict__ Wsrc, const float* __restrict__ bsrc,
                            const float* __restrict__ Wdst, const float* __restrict__ bdst,
                            const float* __restrict__ attn,
                            float* __restrict__ U, float* __restrict__ Cc) {
  int t = blockIdx.x * blockDim.x + threadIdx.x;
  if (t < 4096) {
    int side = t >> 11;
    int r = (t >> 8) & 7;
    int c = t & 255;
    const float* W = side ? Wdst : Wsrc;
    float s = 0.f;
    #pragma unroll
    for (int d = 0; d < 16; d++)
      s += attn[r*32 + side*16 + d] * W[(r*16 + d)*256 + c];
    U[t] = s;
  }
  if (t < 16) {
    int side = t >> 3, r = t & 7;
    const float* b = side ? bdst : bsrc;
    float s = 0.f;
    #pragma unroll
    for (int d = 0; d < 16; d++) s += attn[r*32 + side*16 + d] * b[r*16 + d];
    Cc[t] = s;
  }
}

// ---------------- hs = bf16( feat_src @ W_src^T + b_src )  via MFMA 16x16x32
__global__ __launch_bounds__(256) void hs_gemm_mfma(
    const float* __restrict__ A, const float* __restrict__ W,
    const float* __restrict__ bias, __hip_bfloat16* __restrict__ C, int M) {
  __shared__ short As[128][40];
  __shared__ short Bs[128][40];
  int tid = threadIdx.x;
  int lane = tid & 63;
  int wid = tid >> 6;
  int wr = wid >> 1, wc = wid & 1;
  int row0 = blockIdx.x * 128;
  int lr = lane & 15, lk = lane >> 4;
  int sr = tid >> 1;
  int skq = (tid & 1) * 16;
  f32x4 acc[4][4] = {};

  for (int k0 = 0; k0 < 256; k0 += 32) {
    {
      int gr = row0 + sr;
      float4 v0 = {}, v1 = {}, v2 = {}, v3 = {};
      if (gr < M) {
        const float4* p = (const float4*)&A[(size_t)gr*256 + k0 + skq];
        v0 = p[0]; v1 = p[1]; v2 = p[2]; v3 = p[3];
      }
      bf16x8 t0, t1;
      t0[0]=f2bf(v0.x); t0[1]=f2bf(v0.y); t0[2]=f2bf(v0.z); t0[3]=f2bf(v0.w);
      t0[4]=f2bf(v1.x); t0[5]=f2bf(v1.y); t0[6]=f2bf(v1.z); t0[7]=f2bf(v1.w);
      t1[0]=f2bf(v2.x); t1[1]=f2bf(v2.y); t1[2]=f2bf(v2.z); t1[3]=f2bf(v2.w);
      t1[4]=f2bf(v3.x); t1[5]=f2bf(v3.y); t1[6]=f2bf(v3.z); t1[7]=f2bf(v3.w);
      *(bf16x8*)&As[sr][skq]     = t0;
      *(bf16x8*)&As[sr][skq + 8] = t1;
    }
    {
      const float4* p = (const float4*)&W[(size_t)sr*256 + k0 + skq];
      float4 v0 = p[0], v1 = p[1], v2 = p[2], v3 = p[3];
      bf16x8 t0, t1;
      t0[0]=f2bf(v0.x); t0[1]=f2bf(v0.y); t0[2]=f2bf(v0.z); t0[3]=f2bf(v0.w);
      t0[4]=f2bf(v1.x); t0[5]=f2bf(v1.y); t0[6]=f2bf(v1.z); t0[7]=f2bf(v1.w);
      t1[0]=f2bf(v2.x); t1[1]=f2bf(v2.y); t1[2]=f2bf(v2.z); t1[3]=f2bf(v2.w);
      t1[4]=f2bf(v3.x); t1[5]=f2bf(v3.y); t1[6]=f2bf(v3.z); t1[7]=f2bf(v3.w);
      *(bf16x8*)&Bs[sr][skq]     = t0;
      *(bf16x8*)&Bs[sr][skq + 8] = t1;
    }
    __syncthreads();
    bf16x8 af[4], bfr[4];
    #pragma unroll
    for (int m = 0; m < 4; m++)
      af[m] = *(const bf16x8*)&As[wr*64 + m*16 + lr][lk*8];
    #pragma unroll
    for (int n = 0; n < 4; n++)
      bfr[n] = *(const bf16x8*)&Bs[wc*64 + n*16 + lr][lk*8];
    #pragma unroll
    for (int m = 0; m < 4; m++)
      #pragma unroll
      for (int n = 0; n < 4; n++)
        acc[m][n] = __builtin_amdgcn_mfma_f32_16x16x32_bf16(af[m], bfr[n], acc[m][n], 0, 0, 0);
    __syncthreads();
  }
  #pragma unroll
  for (int m = 0; m < 4; m++) {
    int r0 = row0 + wr*64 + m*16 + lk*4;
    #pragma unroll
    for (int n = 0; n < 4; n++) {
      int col = wc*64 + n*16 + lr;
      float bv = bias[col];
      #pragma unroll
      for (int j = 0; j < 4; j++) {
        int gr = r0 + j;
        if (gr < M) C[(size_t)gr*128 + col] = __float2bfloat16(acc[m][n][j] + bv);
      }
    }
  }
}

// ---------------- el from bf16 hs
__global__ __launch_bounds__(256) void el_from_hs(const __hip_bfloat16* __restrict__ hs,
    const float* __restrict__ attn, float* __restrict__ el) {
  int w = threadIdx.x >> 6, lane = threadIdx.x & 63;
  int n = blockIdx.x * 4 + w;
  if (n >= N_SRCC) return;
  int h = lane >> 3, d0 = (lane & 7) * 2;
  unsigned v = *(const unsigned*)&hs[(size_t)n*128 + h*16 + d0];
  float p = bf2f(v & 0xffffu) * attn[h*32 + d0] + bf2f(v >> 16) * attn[h*32 + d0 + 1];
  p += __shfl_xor(p, 1); p += __shfl_xor(p, 2); p += __shfl_xor(p, 4);
  if ((lane & 7) == 0) el[n*8 + h] = p;
}

// ---------------- er: feat_dst[j,:]·U_dst[h,:] + Cc_dst[h]
__global__ __launch_bounds__(256) void elr_kernel(const float* __restrict__ feat,
    const float* __restrict__ U, const float* __restrict__ Cc,
    float* __restrict__ outv, int N) {
  int w = threadIdx.x >> 6, lane = threadIdx.x & 63;
  int j = blockIdx.x * 4 + w;
  if (j >= N) return;
  float4 f = *(const float4*)&feat[(size_t)j*256 + lane*4];
  float p[8];
  #pragma unroll
  for (int h = 0; h < 8; h++) {
    float4 u = *(const float4*)&U[h*256 + lane*4];
    p[h] = f.x*u.x + f.y*u.y + f.z*u.z + f.w*u.w;
  }
  #pragma unroll
  for (int h = 0; h < 8; h++)
    #pragma unroll
    for (int m = 32; m; m >>= 1) p[h] += __shfl_xor(p[h], m);
  if (lane < 8) outv[j*8 + lane] = p[lane] + Cc[lane];
}

// ---------------- bucket totals (block-local LDS hist, one global atomic per bin per block)
__global__ __launch_bounds__(256) void bucket_hist(const int* __restrict__ dst, int* __restrict__ gCnt) {
  __shared__ int h[NBUK];
  for (int i = threadIdx.x; i < NBUK; i += 256) h[i] = 0;
  __syncthreads();
  int start = blockIdx.x * EPB;
  int end = min(start + EPB, N_EDG);
  for (int e = start + threadIdx.x; e < end; e += 256)
    atomicAdd(&h[dst[e] / DPB], 1);
  __syncthreads();
  for (int i = threadIdx.x; i < NBUK; i += 256)
    if (h[i]) atomicAdd(&gCnt[i], h[i]);
}

// ---------------- exclusive scan of 500 bucket counts
__global__ __launch_bounds__(512) void bucket_scan(const int* __restrict__ gCnt,
                                                   int* __restrict__ bBase, int* __restrict__ bCur) {
  __shared__ int s[512];
  int t = threadIdx.x;
  int x = (t < NBUK) ? gCnt[t] : 0;
  s[t] = x; __syncthreads();
  for (int d = 1; d < 512; d <<= 1) {
    int v = (t >= d) ? s[t-d] : 0;
    __syncthreads(); s[t] += v; __syncthreads();
  }
  if (t < NBUK) { bBase[t] = s[t] - x; bCur[t] = s[t] - x; }
}

// ---------------- partition edges into buckets: entry = src | dstlow<<16
__global__ __launch_bounds__(256) void partition_k(const int* __restrict__ src, const int* __restrict__ dst,
                                                   int* __restrict__ bCur, unsigned* __restrict__ bData) {
  __shared__ int h[NBUK];
  __shared__ int cur[NBUK];
  for (int i = threadIdx.x; i < NBUK; i += 256) h[i] = 0;
  __syncthreads();
  int start = blockIdx.x * EPB;
  int end = min(start + EPB, N_EDG);
  for (int e = start + threadIdx.x; e < end; e += 256)
    atomicAdd(&h[dst[e] / DPB], 1);
  __syncthreads();
  for (int i = threadIdx.x; i < NBUK; i += 256) {
    int c = h[i];
    cur[i] = c ? atomicAdd(&bCur[i], c) : 0;
  }
  __syncthreads();
  for (int e = start + threadIdx.x; e < end; e += 256) {
    int d = dst[e], b = d / DPB;
    int pos = atomicAdd(&cur[b], 1);
    bData[pos] = (unsigned)src[e] | ((unsigned)(d - b*DPB) << 16);
  }
}

// ---------------- fused per-bucket softmax + aggregation (one block per bucket)
__global__ __launch_bounds__(256) void fused_agg(
    const unsigned* __restrict__ bData, const int* __restrict__ bBase, const int* __restrict__ gCnt,
    const __hip_bfloat16* __restrict__ hs, const float* __restrict__ el,
    const float* __restrict__ er, float* __restrict__ out) {
  __shared__ float accE[DPB*64];   // even channels: [d][c/2]
  __shared__ float accO[DPB*64];   // odd channels
  __shared__ float denom[DPB*8];
  __shared__ float erS[DPB*8];
  int b = blockIdx.x;
  int t = threadIdx.x;
  int d0 = b * DPB;
  for (int i = t; i < DPB*64; i += 256) { accE[i] = 0.f; accO[i] = 0.f; }
  for (int i = t; i < DPB*8; i += 256) { denom[i] = 0.f; erS[i] = er[d0*8 + i]; }
  __syncthreads();
  int w = t >> 6, lane = t & 63;
  int h = lane >> 3;                 // head for channels 2*lane, 2*lane+1
  int start = bBase[b], end = start + gCnt[b];

  #define AGG_BODY(E) { \
    unsigned ent = bData[E]; \
    int s = ent & 0xffffu; \
    int dl = ent >> 16; \
    float ev = el[s*8 + h] + erS[dl*8 + h]; \
    ev = ev >= 0.f ? ev : 0.2f * ev; \
    float wg = __expf(ev); \
    unsigned hv = *(const unsigned*)&hs[(size_t)s*128 + lane*2]; \
    atomicAdd(&accE[dl*64 + lane], wg * bf2f(hv & 0xffffu)); \
    atomicAdd(&accO[dl*64 + lane], wg * bf2f(hv >> 16)); \
    if ((lane & 7) == 0) atomicAdd(&denom[dl*8 + h], wg); \
  }

  int e = start + w;
  for (; e + 4 < end; e += 8) { AGG_BODY(e); AGG_BODY(e + 4); }
  if (e < end) AGG_BODY(e);
  #undef AGG_BODY
  __syncthreads();

  for (int i = t; i < DPB*128; i += 256) {
    int d = i >> 7, c = i & 127;
    float dn = denom[d*8 + (c >> 4)];
    float v = (c & 1) ? accO[d*64 + (c >> 1)] : accE[d*64 + (c >> 1)];
    out[(size_t)(d0 + d)*128 + c] = dn > 0.f ? v / dn : 0.f;
  }
}

extern "C" void kernel_launch(void* const* d_in, const int* in_sizes, int n_in,
                              void* d_out, int out_size, void* d_ws, size_t ws_size,
                              hipStream_t stream) {
  const float* feat_src = (const float*)d_in[0];
  const float* feat_dst = (const float*)d_in[1];
  const float* W_src = (const float*)d_in[2];
  const float* b_src = (const float*)d_in[3];
  const float* W_dst = (const float*)d_in[4];
  const float* b_dst = (const float*)d_in[5];
  const float* attn  = (const float*)d_in[6];
  const int* src_idx = (const int*)d_in[7];
  const int* dst_idx = (const int*)d_in[8];
  float* out = (float*)d_out;

  __hip_bfloat16* hs_bf = (__hip_bfloat16*)d_ws;        // 12.8 MB
  float* el = (float*)(hs_bf + (size_t)N_SRCC*128);     // 400,000 f
  float* er = el + (size_t)N_SRCC*8;                    // 400,000 f
  float* U  = er + (size_t)N_DSTC*8;                    // 4096 f
  float* Cc = U + 4096;                                 // 16 f
  int* gCnt = (int*)(Cc + 16);                          // 500 i
  int* bBase = gCnt + NBUK;                             // 500 i
  int* bCur  = bBase + NBUK;                            // 500 i
  unsigned* bData = (unsigned*)(bCur + NBUK);           // 800,000 u32

  fold_kernel<<<16, 256, 0, stream>>>(W_src, b_src, W_dst, b_dst, attn, U, Cc);
  hs_gemm_mfma<<<(N_SRCC + 127)/128, 256, 0, stream>>>(feat_src, W_src, b_src, hs_bf, N_SRCC);
  el_from_hs<<<(N_SRCC + 3)/4, 256, 0, stream>>>(hs_bf, attn, el);
  elr_kernel<<<(N_DSTC + 3)/4, 256, 0, stream>>>(feat_dst, U + 2048, Cc + 8, er, N_DSTC);
  hipMemsetAsync(gCnt, 0, NBUK*sizeof(int), stream);
  bucket_hist<<<NPB, 256, 0, stream>>>(dst_idx, gCnt);
  bucket_scan<<<1, 512, 0, stream>>>(gCnt, bBase, bCur);
  partition_k<<<NPB, 256, 0, stream>>>(src_idx, dst_idx, bCur, bData);
  fused_agg<<<NBUK, 256, 0, stream>>>(bData, bBase, gCnt, hs_bf, el, er, out);
}

// Round 4
// 141.433 us; speedup vs baseline: 4.9087x; 4.9087x over previous
//
#include <hip/hip_runtime.h>
#include <hip/hip_bf16.h>

#define N_SRCC 50000
#define N_DSTC 50000
#define N_EDG 800000
#define NBUK 500
#define DPB 100        // dst nodes per bucket; NBUK*DPB == N_DSTC
#define EPB 3334       // edges per partition block
#define NPB 240        // ceil(N_EDG/EPB)

typedef __attribute__((ext_vector_type(8))) short bf16x8;
typedef __attribute__((ext_vector_type(4))) float f32x4;
typedef __attribute__((ext_vector_type(8))) unsigned short us8;

__device__ inline short f2bf(float x) {
  __hip_bfloat16 b = __float2bfloat16(x);
  return *reinterpret_cast<short*>(&b);
}
__device__ inline float bf2f(unsigned hi16) {  // bf16 bits in low 16
  union { unsigned u; float f; } c; c.u = hi16 << 16; return c.f;
}

// ---------------- fold: u[k,:] = sum_d a[k,d]*W[k*16+d,:], c[k] = sum_d a[k,d]*b[k*16+d]
__global__ void fold_kernel(const float* __restrict__ Wsrc, const float* __restrict__ bsrc,
                            const float* __restrict__ Wdst, const float* __restrict__ bdst,
                            const float* __restrict__ attn,
                            float* __restrict__ U, float* __restrict__ Cc) {
  int t = blockIdx.x * blockDim.x + threadIdx.x;
  if (t < 4096) {
    int side = t >> 11;
    int r = (t >> 8) & 7;
    int c = t & 255;
    const float* W = side ? Wdst : Wsrc;
    float s = 0.f;
    #pragma unroll
    for (int d = 0; d < 16; d++)
      s += attn[r*32 + side*16 + d] * W[(r*16 + d)*256 + c];
    U[t] = s;
  }
  if (t < 16) {
    int side = t >> 3, r = t & 7;
    const float* b = side ? bdst : bsrc;
    float s = 0.f;
    #pragma unroll
    for (int d = 0; d < 16; d++) s += attn[r*32 + side*16 + d] * b[r*16 + d];
    Cc[t] = s;
  }
}

// ---------------- hs = bf16( feat_src @ W_src^T + b_src )  via MFMA 16x16x32
__global__ __launch_bounds__(256) void hs_gemm_mfma(
    const float* __restrict__ A, const float* __restrict__ W,
    const float* __restrict__ bias, __hip_bfloat16* __restrict__ C, int M) {
  __shared__ short As[128][40];
  __shared__ short Bs[128][40];
  int tid = threadIdx.x;
  int lane = tid & 63;
  int wid = tid >> 6;
  int wr = wid >> 1, wc = wid & 1;
  int row0 = blockIdx.x * 128;
  int lr = lane & 15, lk = lane >> 4;
  int sr = tid >> 1;
  int skq = (tid & 1) * 16;
  f32x4 acc[4][4] = {};

  for (int k0 = 0; k0 < 256; k0 += 32) {
    {
      int gr = row0 + sr;
      float4 v0 = {}, v1 = {}, v2 = {}, v3 = {};
      if (gr < M) {
        const float4* p = (const float4*)&A[(size_t)gr*256 + k0 + skq];
        v0 = p[0]; v1 = p[1]; v2 = p[2]; v3 = p[3];
      }
      bf16x8 t0, t1;
      t0[0]=f2bf(v0.x); t0[1]=f2bf(v0.y); t0[2]=f2bf(v0.z); t0[3]=f2bf(v0.w);
      t0[4]=f2bf(v1.x); t0[5]=f2bf(v1.y); t0[6]=f2bf(v1.z); t0[7]=f2bf(v1.w);
      t1[0]=f2bf(v2.x); t1[1]=f2bf(v2.y); t1[2]=f2bf(v2.z); t1[3]=f2bf(v2.w);
      t1[4]=f2bf(v3.x); t1[5]=f2bf(v3.y); t1[6]=f2bf(v3.z); t1[7]=f2bf(v3.w);
      *(bf16x8*)&As[sr][skq]     = t0;
      *(bf16x8*)&As[sr][skq + 8] = t1;
    }
    {
      const float4* p = (const float4*)&W[(size_t)sr*256 + k0 + skq];
      float4 v0 = p[0], v1 = p[1], v2 = p[2], v3 = p[3];
      bf16x8 t0, t1;
      t0[0]=f2bf(v0.x); t0[1]=f2bf(v0.y); t0[2]=f2bf(v0.z); t0[3]=f2bf(v0.w);
      t0[4]=f2bf(v1.x); t0[5]=f2bf(v1.y); t0[6]=f2bf(v1.z); t0[7]=f2bf(v1.w);
      t1[0]=f2bf(v2.x); t1[1]=f2bf(v2.y); t1[2]=f2bf(v2.z); t1[3]=f2bf(v2.w);
      t1[4]=f2bf(v3.x); t1[5]=f2bf(v3.y); t1[6]=f2bf(v3.z); t1[7]=f2bf(v3.w);
      *(bf16x8*)&Bs[sr][skq]     = t0;
      *(bf16x8*)&Bs[sr][skq + 8] = t1;
    }
    __syncthreads();
    bf16x8 af[4], bfr[4];
    #pragma unroll
    for (int m = 0; m < 4; m++)
      af[m] = *(const bf16x8*)&As[wr*64 + m*16 + lr][lk*8];
    #pragma unroll
    for (int n = 0; n < 4; n++)
      bfr[n] = *(const bf16x8*)&Bs[wc*64 + n*16 + lr][lk*8];
    #pragma unroll
    for (int m = 0; m < 4; m++)
      #pragma unroll
      for (int n = 0; n < 4; n++)
        acc[m][n] = __builtin_amdgcn_mfma_f32_16x16x32_bf16(af[m], bfr[n], acc[m][n], 0, 0, 0);
    __syncthreads();
  }
  #pragma unroll
  for (int m = 0; m < 4; m++) {
    int r0 = row0 + wr*64 + m*16 + lk*4;
    #pragma unroll
    for (int n = 0; n < 4; n++) {
      int col = wc*64 + n*16 + lr;
      float bv = bias[col];
      #pragma unroll
      for (int j = 0; j < 4; j++) {
        int gr = r0 + j;
        if (gr < M) C[(size_t)gr*128 + col] = __float2bfloat16(acc[m][n][j] + bv);
      }
    }
  }
}

// ---------------- el from bf16 hs
__global__ __launch_bounds__(256) void el_from_hs(const __hip_bfloat16* __restrict__ hs,
    const float* __restrict__ attn, float* __restrict__ el) {
  int w = threadIdx.x >> 6, lane = threadIdx.x & 63;
  int n = blockIdx.x * 4 + w;
  if (n >= N_SRCC) return;
  int h = lane >> 3, d0 = (lane & 7) * 2;
  unsigned v = *(const unsigned*)&hs[(size_t)n*128 + h*16 + d0];
  float p = bf2f(v & 0xffffu) * attn[h*32 + d0] + bf2f(v >> 16) * attn[h*32 + d0 + 1];
  p += __shfl_xor(p, 1); p += __shfl_xor(p, 2); p += __shfl_xor(p, 4);
  if ((lane & 7) == 0) el[n*8 + h] = p;
}

// ---------------- er: feat_dst[j,:]·U_dst[h,:] + Cc_dst[h]
__global__ __launch_bounds__(256) void elr_kernel(const float* __restrict__ feat,
    const float* __restrict__ U, const float* __restrict__ Cc,
    float* __restrict__ outv, int N) {
  int w = threadIdx.x >> 6, lane = threadIdx.x & 63;
  int j = blockIdx.x * 4 + w;
  if (j >= N) return;
  float4 f = *(const float4*)&feat[(size_t)j*256 + lane*4];
  float p[8];
  #pragma unroll
  for (int h = 0; h < 8; h++) {
    float4 u = *(const float4*)&U[h*256 + lane*4];
    p[h] = f.x*u.x + f.y*u.y + f.z*u.z + f.w*u.w;
  }
  #pragma unroll
  for (int h = 0; h < 8; h++)
    #pragma unroll
    for (int m = 32; m; m >>= 1) p[h] += __shfl_xor(p[h], m);
  if (lane < 8) outv[j*8 + lane] = p[lane] + Cc[lane];
}

// ---------------- bucket totals (LDS hist, one global atomic per bin per block)
__global__ __launch_bounds__(256) void bucket_hist(const int* __restrict__ dst, int* __restrict__ gCnt) {
  __shared__ int h[NBUK];
  for (int i = threadIdx.x; i < NBUK; i += 256) h[i] = 0;
  __syncthreads();
  int start = blockIdx.x * EPB;
  int end = min(start + EPB, N_EDG);
  for (int e = start + threadIdx.x; e < end; e += 256)
    atomicAdd(&h[dst[e] / DPB], 1);
  __syncthreads();
  for (int i = threadIdx.x; i < NBUK; i += 256)
    if (h[i]) atomicAdd(&gCnt[i], h[i]);
}

// ---------------- exclusive scan of 500 bucket counts
__global__ __launch_bounds__(512) void bucket_scan(const int* __restrict__ gCnt,
                                                   int* __restrict__ bBase, int* __restrict__ bCur,
                                                   int* __restrict__ off) {
  __shared__ int s[512];
  int t = threadIdx.x;
  int x = (t < NBUK) ? gCnt[t] : 0;
  s[t] = x; __syncthreads();
  for (int d = 1; d < 512; d <<= 1) {
    int v = (t >= d) ? s[t-d] : 0;
    __syncthreads(); s[t] += v; __syncthreads();
  }
  if (t < NBUK) { bBase[t] = s[t] - x; bCur[t] = s[t] - x; }
  if (t == 0) off[N_DSTC] = N_EDG;
}

// ---------------- partition edges into buckets: entry = src | dstlow<<16
__global__ __launch_bounds__(256) void partition_k(const int* __restrict__ src, const int* __restrict__ dst,
                                                   int* __restrict__ bCur, unsigned* __restrict__ bData) {
  __shared__ int h[NBUK];
  __shared__ int cur[NBUK];
  for (int i = threadIdx.x; i < NBUK; i += 256) h[i] = 0;
  __syncthreads();
  int start = blockIdx.x * EPB;
  int end = min(start + EPB, N_EDG);
  for (int e = start + threadIdx.x; e < end; e += 256)
    atomicAdd(&h[dst[e] / DPB], 1);
  __syncthreads();
  for (int i = threadIdx.x; i < NBUK; i += 256) {
    int c = h[i];
    cur[i] = c ? atomicAdd(&bCur[i], c) : 0;
  }
  __syncthreads();
  for (int e = start + threadIdx.x; e < end; e += 256) {
    int d = dst[e], b = d / DPB;
    int pos = atomicAdd(&cur[b], 1);
    bData[pos] = (unsigned)src[e] | ((unsigned)(d - b*DPB) << 16);
  }
}

// ---------------- per-bucket counting sort -> dst-sorted srcS + per-dst off
// One block per bucket; all scattered writes land in this bucket's private
// ~6.4KB region (assembled in one L2, ~1x write amplification).
__global__ __launch_bounds__(256) void sort_bucket(const unsigned* __restrict__ bData,
    const int* __restrict__ bBase, const int* __restrict__ gCnt,
    int* __restrict__ off, int* __restrict__ srcS) {
  __shared__ int hist[DPB];
  __shared__ int s[128];
  __shared__ int cur[DPB];
  int b = blockIdx.x, t = threadIdx.x;
  int start = bBase[b], cnt = gCnt[b];
  for (int i = t; i < DPB; i += 256) hist[i] = 0;
  __syncthreads();
  for (int e = t; e < cnt; e += 256) atomicAdd(&hist[bData[start + e] >> 16], 1);
  __syncthreads();
  if (t < 128) s[t] = (t < DPB) ? hist[t] : 0;
  __syncthreads();
  for (int d = 1; d < 128; d <<= 1) {
    int v = (t < 128 && t >= d) ? s[t - d] : 0;
    __syncthreads();
    if (t < 128) s[t] += v;
    __syncthreads();
  }
  if (t < DPB) {
    int excl = s[t] - hist[t];
    cur[t] = excl;
    off[b * DPB + t] = start + excl;
  }
  __syncthreads();
  for (int e = t; e < cnt; e += 256) {
    unsigned ent = bData[start + e];
    int pos = atomicAdd(&cur[ent >> 16], 1);
    srcS[start + pos] = (int)(ent & 0xffffu);
  }
}

// ---------------- aggregation: one wave per dst node, 4 edges in flight,
// 16 lanes x 8 bf16 channels per edge; single pass (|e|<=~3 so exp(e) safe).
__global__ __launch_bounds__(256) void aggregate(
    const __hip_bfloat16* __restrict__ hs, const float* __restrict__ el,
    const float* __restrict__ er, const int* __restrict__ off,
    const int* __restrict__ srcS, float* __restrict__ out) {
  int w = threadIdx.x >> 6;
  int lane = threadIdx.x & 63;
  int j = blockIdx.x * 4 + w;
  if (j >= N_DSTC) return;
  int g = lane >> 4;        // edge slot 0..3
  int q = lane & 15;        // channel group: channels q*8..q*8+7
  int h = q >> 1;           // head
  int e0 = off[j], e1 = off[j + 1];
  float erh = er[j*8 + h];
  float acc[8] = {};
  float denom = 0.f;
  for (int e = e0 + g; e < e1; e += 4) {
    int s = srcS[e];
    float ev = el[s*8 + h] + erh;
    ev = ev >= 0.f ? ev : 0.2f * ev;
    float wg = __expf(ev);
    denom += wg;
    us8 hv = *(const us8*)&hs[(size_t)s*128 + q*8];
    #pragma unroll
    for (int c = 0; c < 8; c++) {
      union { unsigned u; float f; } cv;
      cv.u = ((unsigned)hv[c]) << 16;
      acc[c] = fmaf(wg, cv.f, acc[c]);
    }
  }
  #pragma unroll
  for (int c = 0; c < 8; c++) {
    acc[c] += __shfl_xor(acc[c], 16);
    acc[c] += __shfl_xor(acc[c], 32);
  }
  denom += __shfl_xor(denom, 16);
  denom += __shfl_xor(denom, 32);
  if (g == 0) {
    float inv = (e1 > e0) ? 1.f / denom : 0.f;
    float4 r0, r1;
    r0.x = acc[0]*inv; r0.y = acc[1]*inv; r0.z = acc[2]*inv; r0.w = acc[3]*inv;
    r1.x = acc[4]*inv; r1.y = acc[5]*inv; r1.z = acc[6]*inv; r1.w = acc[7]*inv;
    *(float4*)&out[(size_t)j*128 + q*8]     = r0;
    *(float4*)&out[(size_t)j*128 + q*8 + 4] = r1;
  }
}

extern "C" void kernel_launch(void* const* d_in, const int* in_sizes, int n_in,
                              void* d_out, int out_size, void* d_ws, size_t ws_size,
                              hipStream_t stream) {
  const float* feat_src = (const float*)d_in[0];
  const float* feat_dst = (const float*)d_in[1];
  const float* W_src = (const float*)d_in[2];
  const float* b_src = (const float*)d_in[3];
  const float* W_dst = (const float*)d_in[4];
  const float* b_dst = (const float*)d_in[5];
  const float* attn  = (const float*)d_in[6];
  const int* src_idx = (const int*)d_in[7];
  const int* dst_idx = (const int*)d_in[8];
  float* out = (float*)d_out;

  __hip_bfloat16* hs_bf = (__hip_bfloat16*)d_ws;        // 12.8 MB
  float* el = (float*)(hs_bf + (size_t)N_SRCC*128);     // 400,000 f
  float* er = el + (size_t)N_SRCC*8;                    // 400,000 f
  float* U  = er + (size_t)N_DSTC*8;                    // 4096 f
  float* Cc = U + 4096;                                 // 16 f
  int* gCnt = (int*)(Cc + 16);                          // 500 i
  int* bBase = gCnt + NBUK;                             // 500 i
  int* bCur  = bBase + NBUK;                            // 500 i
  int* off   = bCur + NBUK;                             // 50001 i
  int* srcS  = off + N_DSTC + 1;                        // 800,000 i
  unsigned* bData = (unsigned*)(srcS + N_EDG);          // 800,000 u32

  fold_kernel<<<16, 256, 0, stream>>>(W_src, b_src, W_dst, b_dst, attn, U, Cc);
  hs_gemm_mfma<<<(N_SRCC + 127)/128, 256, 0, stream>>>(feat_src, W_src, b_src, hs_bf, N_SRCC);
  el_from_hs<<<(N_SRCC + 3)/4, 256, 0, stream>>>(hs_bf, attn, el);
  elr_kernel<<<(N_DSTC + 3)/4, 256, 0, stream>>>(feat_dst, U + 2048, Cc + 8, er, N_DSTC);
  hipMemsetAsync(gCnt, 0, NBUK*sizeof(int), stream);
  bucket_hist<<<NPB, 256, 0, stream>>>(dst_idx, gCnt);
  bucket_scan<<<1, 512, 0, stream>>>(gCnt, bBase, bCur, off);
  partition_k<<<NPB, 256, 0, stream>>>(src_idx, dst_idx, bCur, bData);
  sort_bucket<<<NBUK, 256, 0, stream>>>(bData, bBase, gCnt, off, srcS);
  aggregate<<<(N_DSTC + 3)/4, 256, 0, stream>>>(hs_bf, el, er, off, srcS, out);
}

// Round 5
// 123.268 us; speedup vs baseline: 5.6320x; 1.1474x over previous
//
#include <hip/hip_runtime.h>
#include <hip/hip_bf16.h>

#define N_SRCC 50000
#define N_DSTC 50000
#define N_EDG 800000
#define NBUK 500
#define DPB 100        // dst nodes per bucket
#define EPB 3334       // edges per partition block
#define NPB 240        // ceil(N_EDG/EPB)
#define ERB 6250       // er blocks (8 nodes each)

typedef __attribute__((ext_vector_type(8))) short bf16x8;
typedef __attribute__((ext_vector_type(4))) float f32x4;
typedef __attribute__((ext_vector_type(8))) unsigned short us8;

__device__ inline short f2bf(float x) {
  __hip_bfloat16 b = __float2bfloat16(x);
  return *reinterpret_cast<short*>(&b);
}
__device__ inline float bf2f(unsigned hi16) {
  union { unsigned u; float f; } c; c.u = hi16 << 16; return c.f;
}

// ---------------- fold: U, Cc, W_src->bf16, zero gCnt
__global__ void fold_kernel(const float* __restrict__ Wsrc, const float* __restrict__ bsrc,
                            const float* __restrict__ Wdst, const float* __restrict__ bdst,
                            const float* __restrict__ attn,
                            float* __restrict__ U, float* __restrict__ Cc,
                            short* __restrict__ Wbf, int* __restrict__ gCnt) {
  int t = blockIdx.x * blockDim.x + threadIdx.x;   // 4096 threads
  if (t < 4096) {
    int side = t >> 11;
    int r = (t >> 8) & 7;
    int c = t & 255;
    const float* W = side ? Wdst : Wsrc;
    float s = 0.f;
    #pragma unroll
    for (int d = 0; d < 16; d++)
      s += attn[r*32 + side*16 + d] * W[(r*16 + d)*256 + c];
    U[t] = s;
    // convert W_src to bf16: elems t*8 .. t*8+7  (128*256 = 32768 = 4096*8)
    const float4* p = (const float4*)&Wsrc[t*8];
    float4 v0 = p[0], v1 = p[1];
    bf16x8 w;
    w[0]=f2bf(v0.x); w[1]=f2bf(v0.y); w[2]=f2bf(v0.z); w[3]=f2bf(v0.w);
    w[4]=f2bf(v1.x); w[5]=f2bf(v1.y); w[6]=f2bf(v1.z); w[7]=f2bf(v1.w);
    *(bf16x8*)&Wbf[t*8] = w;
  }
  if (t < 16) {
    int side = t >> 3, r = t & 7;
    const float* b = side ? bdst : bsrc;
    float s = 0.f;
    #pragma unroll
    for (int d = 0; d < 16; d++) s += attn[r*32 + side*16 + d] * b[r*16 + d];
    Cc[t] = s;
  }
  if (t < NBUK) gCnt[t] = 0;
}

// ---------------- hs = bf16(feat_src @ W^T + b) via MFMA; el fused in epilogue
// 256-row tile, 512 threads (8 waves, 4x2 wave grid)
__global__ __launch_bounds__(512) void hs_gemm_mfma(
    const float* __restrict__ A, const short* __restrict__ Wbf,
    const float* __restrict__ bias, const float* __restrict__ attn,
    __hip_bfloat16* __restrict__ C, float* __restrict__ el, int M) {
  __shared__ short As[256][40];
  __shared__ short Bs[128][40];
  int tid = threadIdx.x;
  int lane = tid & 63, wid = tid >> 6;
  int wr = wid >> 1, wc = wid & 1;
  int row0 = blockIdx.x * 256;
  int lr = lane & 15, lk = lane >> 4;
  int sr = tid >> 1, skq = (tid & 1) * 16;
  int br = tid >> 2, bq = (tid & 3) * 8;
  f32x4 acc[4][4] = {};

  for (int k0 = 0; k0 < 256; k0 += 32) {
    {
      int gr = row0 + sr;
      float4 v0 = {}, v1 = {}, v2 = {}, v3 = {};
      if (gr < M) {
        const float4* p = (const float4*)&A[(size_t)gr*256 + k0 + skq];
        v0 = p[0]; v1 = p[1]; v2 = p[2]; v3 = p[3];
      }
      bf16x8 t0, t1;
      t0[0]=f2bf(v0.x); t0[1]=f2bf(v0.y); t0[2]=f2bf(v0.z); t0[3]=f2bf(v0.w);
      t0[4]=f2bf(v1.x); t0[5]=f2bf(v1.y); t0[6]=f2bf(v1.z); t0[7]=f2bf(v1.w);
      t1[0]=f2bf(v2.x); t1[1]=f2bf(v2.y); t1[2]=f2bf(v2.z); t1[3]=f2bf(v2.w);
      t1[4]=f2bf(v3.x); t1[5]=f2bf(v3.y); t1[6]=f2bf(v3.z); t1[7]=f2bf(v3.w);
      *(bf16x8*)&As[sr][skq]     = t0;
      *(bf16x8*)&As[sr][skq + 8] = t1;
    }
    *(bf16x8*)&Bs[br][bq] = *(const bf16x8*)&Wbf[br*256 + k0 + bq];
    __syncthreads();
    bf16x8 af[4], bfr[4];
    #pragma unroll
    for (int m = 0; m < 4; m++)
      af[m] = *(const bf16x8*)&As[wr*64 + m*16 + lr][lk*8];
    #pragma unroll
    for (int n = 0; n < 4; n++)
      bfr[n] = *(const bf16x8*)&Bs[wc*64 + n*16 + lr][lk*8];
    #pragma unroll
    for (int m = 0; m < 4; m++)
      #pragma unroll
      for (int n = 0; n < 4; n++)
        acc[m][n] = __builtin_amdgcn_mfma_f32_16x16x32_bf16(af[m], bfr[n], acc[m][n], 0, 0, 0);
    __syncthreads();
  }
  // epilogue: C write + fused el (head h = wc*4+n owns cols h*16..h*16+15, d = lr)
  #pragma unroll
  for (int m = 0; m < 4; m++) {
    int r0 = row0 + wr*64 + m*16 + lk*4;
    #pragma unroll
    for (int n = 0; n < 4; n++) {
      int col = wc*64 + n*16 + lr;
      int h = wc*4 + n;
      float bv = bias[col];
      float al = attn[h*32 + lr];
      #pragma unroll
      for (int j = 0; j < 4; j++) {
        int gr = r0 + j;
        float hv = acc[m][n][j] + bv;
        if (gr < M) C[(size_t)gr*128 + col] = __float2bfloat16(hv);
        float p = hv * al;
        p += __shfl_xor(p, 1); p += __shfl_xor(p, 2);
        p += __shfl_xor(p, 4); p += __shfl_xor(p, 8);
        if (lr == 0 && gr < M) el[gr*8 + h] = p;
      }
    }
  }
}

// ---------------- fused: blocks [0,NPB) do bucket histogram; rest do er (2 nodes/wave)
__global__ __launch_bounds__(256) void er_hist(const float* __restrict__ feat,
    const float* __restrict__ U, const float* __restrict__ Cc,
    const int* __restrict__ dst, float* __restrict__ er, int* __restrict__ gCnt) {
  __shared__ int hs_[NBUK];
  int b = blockIdx.x;
  int t = threadIdx.x;
  if (b < NPB) {
    for (int i = t; i < NBUK; i += 256) hs_[i] = 0;
    __syncthreads();
    int start = b * EPB;
    int end = min(start + EPB, N_EDG);
    for (int e = start + t; e < end; e += 256)
      atomicAdd(&hs_[dst[e] / DPB], 1);
    __syncthreads();
    for (int i = t; i < NBUK; i += 256)
      if (hs_[i]) atomicAdd(&gCnt[i], hs_[i]);
    return;
  }
  int w = t >> 6, lane = t & 63;
  int half = lane >> 5, q = lane & 31;
  int j = (b - NPB) * 8 + w*2 + half;
  if (j >= N_DSTC) return;
  const float* fp = &feat[(size_t)j*256 + q*8];
  float4 f0 = *(const float4*)fp;
  float4 f1 = *(const float4*)(fp + 4);
  float p[8];
  #pragma unroll
  for (int h = 0; h < 8; h++) {
    const float4* up = (const float4*)&U[h*256 + q*8];
    float4 u0 = up[0], u1 = up[1];
    p[h] = f0.x*u0.x + f0.y*u0.y + f0.z*u0.z + f0.w*u0.w
         + f1.x*u1.x + f1.y*u1.y + f1.z*u1.z + f1.w*u1.w;
  }
  #pragma unroll
  for (int h = 0; h < 8; h++) {
    p[h] += __shfl_xor(p[h], 1);  p[h] += __shfl_xor(p[h], 2);
    p[h] += __shfl_xor(p[h], 4);  p[h] += __shfl_xor(p[h], 8);
    p[h] += __shfl_xor(p[h], 16);
  }
  if (q < 8) er[j*8 + q] = p[q] + Cc[q];
}

// ---------------- exclusive scan of 500 bucket counts
__global__ __launch_bounds__(512) void bucket_scan(const int* __restrict__ gCnt,
                                                   int* __restrict__ bBase, int* __restrict__ bCur,
                                                   int* __restrict__ off) {
  __shared__ int s[512];
  int t = threadIdx.x;
  int x = (t < NBUK) ? gCnt[t] : 0;
  s[t] = x; __syncthreads();
  for (int d = 1; d < 512; d <<= 1) {
    int v = (t >= d) ? s[t-d] : 0;
    __syncthreads(); s[t] += v; __syncthreads();
  }
  if (t < NBUK) { bBase[t] = s[t] - x; bCur[t] = s[t] - x; }
  if (t == 0) off[N_DSTC] = N_EDG;
}

// ---------------- partition edges into buckets: entry = src | dstlow<<16
__global__ __launch_bounds__(256) void partition_k(const int* __restrict__ src, const int* __restrict__ dst,
                                                   int* __restrict__ bCur, unsigned* __restrict__ bData) {
  __shared__ int h[NBUK];
  __shared__ int cur[NBUK];
  for (int i = threadIdx.x; i < NBUK; i += 256) h[i] = 0;
  __syncthreads();
  int start = blockIdx.x * EPB;
  int end = min(start + EPB, N_EDG);
  for (int e = start + threadIdx.x; e < end; e += 256)
    atomicAdd(&h[dst[e] / DPB], 1);
  __syncthreads();
  for (int i = threadIdx.x; i < NBUK; i += 256) {
    int c = h[i];
    cur[i] = c ? atomicAdd(&bCur[i], c) : 0;
  }
  __syncthreads();
  for (int e = start + threadIdx.x; e < end; e += 256) {
    int d = dst[e], b = d / DPB;
    int pos = atomicAdd(&cur[b], 1);
    bData[pos] = (unsigned)src[e] | ((unsigned)(d - b*DPB) << 16);
  }
}

// ---------------- per-bucket counting sort -> dst-sorted srcS + per-dst off
__global__ __launch_bounds__(256) void sort_bucket(const unsigned* __restrict__ bData,
    const int* __restrict__ bBase, const int* __restrict__ gCnt,
    int* __restrict__ off, int* __restrict__ srcS) {
  __shared__ int hist[DPB];
  __shared__ int s[128];
  __shared__ int cur[DPB];
  int b = blockIdx.x, t = threadIdx.x;
  int start = bBase[b], cnt = gCnt[b];
  for (int i = t; i < DPB; i += 256) hist[i] = 0;
  __syncthreads();
  for (int e = t; e < cnt; e += 256) atomicAdd(&hist[bData[start + e] >> 16], 1);
  __syncthreads();
  if (t < 128) s[t] = (t < DPB) ? hist[t] : 0;
  __syncthreads();
  for (int d = 1; d < 128; d <<= 1) {
    int v = (t < 128 && t >= d) ? s[t - d] : 0;
    __syncthreads();
    if (t < 128) s[t] += v;
    __syncthreads();
  }
  if (t < DPB) {
    int excl = s[t] - hist[t];
    cur[t] = excl;
    off[b * DPB + t] = start + excl;
  }
  __syncthreads();
  for (int e = t; e < cnt; e += 256) {
    unsigned ent = bData[start + e];
    int pos = atomicAdd(&cur[ent >> 16], 1);
    srcS[start + pos] = (int)(ent & 0xffffu);
  }
}

// ---------------- aggregation: one wave per dst, 16 edges in flight
__global__ __launch_bounds__(256) void aggregate(
    const __hip_bfloat16* __restrict__ hs, const float* __restrict__ el,
    const float* __restrict__ er, const int* __restrict__ off,
    const int* __restrict__ srcS, float* __restrict__ out) {
  int w = threadIdx.x >> 6;
  int lane = threadIdx.x & 63;
  int j = blockIdx.x * 4 + w;
  if (j >= N_DSTC) return;
  int g = lane >> 4;        // edge slot 0..3
  int q = lane & 15;        // channel group: channels q*8..q*8+7
  int h = q >> 1;           // head
  int e0 = off[j], e1 = off[j + 1];
  float erh = er[j*8 + h];
  float acc[8] = {};
  float denom = 0.f;

  #define AGG_BODY(E) { \
    int s = srcS[E]; \
    float ev = el[s*8 + h] + erh; \
    ev = ev >= 0.f ? ev : 0.2f * ev; \
    float wg = __expf(ev); \
    denom += wg; \
    us8 hv = *(const us8*)&hs[(size_t)s*128 + q*8]; \
    _Pragma("unroll") \
    for (int c = 0; c < 8; c++) { \
      acc[c] = fmaf(wg, bf2f((unsigned)hv[c]), acc[c]); \
    } \
  }

  int e = e0 + g;
  for (; e + 12 < e1; e += 16) { AGG_BODY(e); AGG_BODY(e+4); AGG_BODY(e+8); AGG_BODY(e+12); }
  for (; e < e1; e += 4) { AGG_BODY(e); }
  #undef AGG_BODY

  #pragma unroll
  for (int c = 0; c < 8; c++) {
    acc[c] += __shfl_xor(acc[c], 16);
    acc[c] += __shfl_xor(acc[c], 32);
  }
  denom += __shfl_xor(denom, 16);
  denom += __shfl_xor(denom, 32);
  if (g == 0) {
    float inv = (e1 > e0) ? 1.f / denom : 0.f;
    float4 r0, r1;
    r0.x = acc[0]*inv; r0.y = acc[1]*inv; r0.z = acc[2]*inv; r0.w = acc[3]*inv;
    r1.x = acc[4]*inv; r1.y = acc[5]*inv; r1.z = acc[6]*inv; r1.w = acc[7]*inv;
    *(float4*)&out[(size_t)j*128 + q*8]     = r0;
    *(float4*)&out[(size_t)j*128 + q*8 + 4] = r1;
  }
}

extern "C" void kernel_launch(void* const* d_in, const int* in_sizes, int n_in,
                              void* d_out, int out_size, void* d_ws, size_t ws_size,
                              hipStream_t stream) {
  const float* feat_src = (const float*)d_in[0];
  const float* feat_dst = (const float*)d_in[1];
  const float* W_src = (const float*)d_in[2];
  const float* b_src = (const float*)d_in[3];
  const float* W_dst = (const float*)d_in[4];
  const float* b_dst = (const float*)d_in[5];
  const float* attn  = (const float*)d_in[6];
  const int* src_idx = (const int*)d_in[7];
  const int* dst_idx = (const int*)d_in[8];
  float* out = (float*)d_out;

  __hip_bfloat16* hs_bf = (__hip_bfloat16*)d_ws;        // 6.4M bf16 = 12.8 MB
  float* el = (float*)(hs_bf + (size_t)N_SRCC*128);     // 400,000 f
  float* er = el + (size_t)N_SRCC*8;                    // 400,000 f
  float* U  = er + (size_t)N_DSTC*8;                    // 4096 f
  float* Cc = U + 4096;                                 // 16 f
  short* Wbf = (short*)(Cc + 16);                       // 32768 bf16 = 64 KB
  int* gCnt = (int*)(Wbf + 32768);                      // 500 i
  int* bBase = gCnt + NBUK;                             // 500 i
  int* bCur  = bBase + NBUK;                            // 500 i
  int* off   = bCur + NBUK;                             // 50001 i
  int* srcS  = off + N_DSTC + 1;                        // 800,000 i
  unsigned* bData = (unsigned*)(srcS + N_EDG);          // 800,000 u32

  fold_kernel<<<16, 256, 0, stream>>>(W_src, b_src, W_dst, b_dst, attn, U, Cc, Wbf, gCnt);
  er_hist<<<NPB + ERB, 256, 0, stream>>>(feat_dst, U + 2048, Cc + 8, dst_idx, er, gCnt);
  bucket_scan<<<1, 512, 0, stream>>>(gCnt, bBase, bCur, off);
  hs_gemm_mfma<<<(N_SRCC + 255)/256, 512, 0, stream>>>(feat_src, Wbf, b_src, attn, hs_bf, el, N_SRCC);
  partition_k<<<NPB, 256, 0, stream>>>(src_idx, dst_idx, bCur, bData);
  sort_bucket<<<NBUK, 256, 0, stream>>>(bData, bBase, gCnt, off, srcS);
  aggregate<<<(N_DSTC + 3)/4, 256, 0, stream>>>(hs_bf, el, er, off, srcS, out);
}